// Round 2
// baseline (24409.117 us; speedup 1.0000x reference)
//
#include <hip/hip_runtime.h>

typedef __attribute__((ext_vector_type(8))) short short8;
typedef __attribute__((ext_vector_type(4))) float f32x4;
typedef unsigned short u16;
typedef unsigned int u32;

#define T_LEN 512
#define BATCH 64
#define HID 400
#define GATES 1200   // 3*HID
#define DIN 800      // layer input width (D == 2H)
#define KTOT 1200    // DIN + HID
#define WSTRIDE 1216 // K padded to 38*32
#define HSTRIDE 416  // HID padded to 13*32

__device__ __forceinline__ u16 f2bf(float f) {
    u32 u = __builtin_bit_cast(u32, f);
    u += 0x7fffu + ((u >> 16) & 1u);
    return (u16)(u >> 16);
}
__device__ __forceinline__ float sigmoidf_(float x) { return 1.f / (1.f + expf(-x)); }

// ---------------- cast kernels ----------------
__global__ void cast_f32_bf16(const float* __restrict__ in, u16* __restrict__ out, int n) {
    for (int i = blockIdx.x * blockDim.x + threadIdx.x; i < n; i += gridDim.x * blockDim.x)
        out[i] = f2bf(in[i]);
}

// W_bf layout: [2][GATES][WSTRIDE], cols >= 1200 zeroed
__global__ void cast_W(const float* __restrict__ fW, const float* __restrict__ bW,
                       u16* __restrict__ W_bf, int layer) {
    const int n = 2 * GATES * WSTRIDE;
    for (int i = blockIdx.x * blockDim.x + threadIdx.x; i < n; i += gridDim.x * blockDim.x) {
        int d = i / (GATES * WSTRIDE);
        int rem = i - d * (GATES * WSTRIDE);
        int r = rem / WSTRIDE;
        int k = rem - r * WSTRIDE;
        const float* src = (d ? bW : fW) + (size_t)layer * GATES * KTOT;
        W_bf[i] = (k < KTOT) ? f2bf(src[(size_t)r * KTOT + k]) : (u16)0;
    }
}

// h_bf: [2 dirs][2 bufs][BATCH][HSTRIDE]; buf0 = h_init, buf1 = 0, pads zeroed
__global__ void init_states(const float* __restrict__ f_init, const float* __restrict__ b_init,
                            u16* __restrict__ h_bf, int layer) {
    const int n = 2 * 2 * BATCH * HSTRIDE;
    for (int i = blockIdx.x * blockDim.x + threadIdx.x; i < n; i += gridDim.x * blockDim.x) {
        int d = i / (2 * BATCH * HSTRIDE);
        int rem = i - d * (2 * BATCH * HSTRIDE);
        int buf = rem / (BATCH * HSTRIDE);
        int rem2 = rem - buf * (BATCH * HSTRIDE);
        int k = rem2 % HSTRIDE;
        const float* src = (d ? b_init : f_init) + layer * 2 * HID;
        h_bf[i] = (k < HID && buf == 0) ? f2bf(src[k]) : (u16)0;
    }
}

// ---------------- persistent per-layer LSTM (both directions, all 512 steps) ----------------
// grid: (25 h-col blocks, 4 batch blocks, 2 dirs) = 200 blocks, 192 threads (3 waves = gates i,j,o)
// Per (batch,dir) group of 25 blocks: monotonic counter/generation barrier per step.
// h exchanged through coherence point via sc0/sc1 bypass stores+loads (keeps W/x hot in L2).
__global__ __launch_bounds__(192) void lstm_persist(
    const u16* __restrict__ x_bf,   // [T*B, DIN]
    const u16* __restrict__ W_bf,   // [2][GATES][WSTRIDE]
    const float* __restrict__ fb_l, // [GATES]
    const float* __restrict__ bb_l, // [GATES]
    const float* __restrict__ masks,// [T*B]
    const float* __restrict__ finit,// [2,HID] (layer slice)
    const float* __restrict__ binit,// [2,HID]
    u16* __restrict__ h_bf,         // [2][2][B][HSTRIDE]
    float* __restrict__ c_end,      // [2][B][HID]
    float* __restrict__ raw,        // [T*B, 2H]
    int* __restrict__ bar)          // [16]: cnt[8], gen[8]
{
    const int dir = blockIdx.z;
    const int pl  = blockIdx.x;           // 0..24 h-col block
    const int bb  = blockIdx.y * 16;      // batch base
    const int tid = threadIdx.x;
    const int lane = tid & 63, gate = tid >> 6;
    const int l15 = lane & 15, hi = lane >> 4;

    int* cnt = bar + (dir * 4 + blockIdx.y);
    int* gen = bar + 8 + (dir * 4 + blockIdx.y);

    __shared__ float gsm[3][16][16];
    __shared__ float c_lds[16][16];

    const float* init = dir ? binit : finit;
    for (int i = tid; i < 256; i += 192)
        c_lds[i >> 4][i & 15] = init[HID + pl * 16 + (i & 15)];

    const int prow = gate * HID + pl * 16 + l15;  // W row
    const float bval = (dir ? bb_l : fb_l)[prow];
    const u16* Brow = W_bf + (size_t)dir * GATES * WSTRIDE + (size_t)prow * WSTRIDE + 8 * hi;

    __syncthreads();

    for (int tf = 0; tf < T_LEN; ++tf) {
        const int t = dir ? (T_LEN - 1 - tf) : tf;
        f32x4 acc = {bval, bval, bval, bval};

        // ---- x part (K = 0..800), normal loads (L2-resident W and x) ----
        const u16* Arow = x_bf + (size_t)(t * BATCH + bb + l15) * DIN + 8 * hi;
#pragma unroll
        for (int kk = 0; kk < 25; ++kk)
            acc = __builtin_amdgcn_mfma_f32_16x16x32_bf16(
                *(const short8*)(Arow + kk * 32), *(const short8*)(Brow + kk * 32), acc, 0, 0, 0);

        // ---- h part (K = 800..1216): cache-bypass loads (device-coherent) ----
        const u16* Hrow = h_bf + (size_t)((dir * 2 + (tf & 1)) * BATCH + bb + l15) * HSTRIDE + 8 * hi;
        short8 hf[13];
        asm volatile(
            "global_load_dwordx4 %[f0],  %[a], off sc0 sc1\n\t"
            "global_load_dwordx4 %[f1],  %[a], off offset:64 sc0 sc1\n\t"
            "global_load_dwordx4 %[f2],  %[a], off offset:128 sc0 sc1\n\t"
            "global_load_dwordx4 %[f3],  %[a], off offset:192 sc0 sc1\n\t"
            "global_load_dwordx4 %[f4],  %[a], off offset:256 sc0 sc1\n\t"
            "global_load_dwordx4 %[f5],  %[a], off offset:320 sc0 sc1\n\t"
            "global_load_dwordx4 %[f6],  %[a], off offset:384 sc0 sc1\n\t"
            "global_load_dwordx4 %[f7],  %[a], off offset:448 sc0 sc1\n\t"
            "global_load_dwordx4 %[f8],  %[a], off offset:512 sc0 sc1\n\t"
            "global_load_dwordx4 %[f9],  %[a], off offset:576 sc0 sc1\n\t"
            "global_load_dwordx4 %[f10], %[a], off offset:640 sc0 sc1\n\t"
            "global_load_dwordx4 %[f11], %[a], off offset:704 sc0 sc1\n\t"
            "global_load_dwordx4 %[f12], %[a], off offset:768 sc0 sc1\n\t"
            "s_waitcnt vmcnt(0)"
            : [f0] "=&v"(hf[0]), [f1] "=&v"(hf[1]), [f2] "=&v"(hf[2]), [f3] "=&v"(hf[3]),
              [f4] "=&v"(hf[4]), [f5] "=&v"(hf[5]), [f6] "=&v"(hf[6]), [f7] "=&v"(hf[7]),
              [f8] "=&v"(hf[8]), [f9] "=&v"(hf[9]), [f10] "=&v"(hf[10]), [f11] "=&v"(hf[11]),
              [f12] "=&v"(hf[12])
            : [a] "v"(Hrow)
            : "memory");
        __builtin_amdgcn_sched_barrier(0);
#pragma unroll
        for (int kk = 0; kk < 13; ++kk)
            acc = __builtin_amdgcn_mfma_f32_16x16x32_bf16(
                hf[kk], *(const short8*)(Brow + (25 + kk) * 32), acc, 0, 0, 0);

        // ---- gate exchange ----
#pragma unroll
        for (int j = 0; j < 4; ++j) gsm[gate][hi * 4 + j][l15] = acc[j];
        __syncthreads();

        // ---- cell update: 128 threads handle 16 batch x 8 col-pairs ----
        if (tid < 128) {
            const int bi = tid >> 3, cp = (tid & 7) * 2;
            const int bg = bb + bi;
            const float m = masks[t * BATCH + bg];
            float h2[2];
#pragma unroll
            for (int q = 0; q < 2; ++q) {
                const int c = cp + q;
                float ig = sigmoidf_(gsm[0][bi][c]);
                float jg = tanhf(gsm[1][bi][c]);
                float og = sigmoidf_(gsm[2][bi][c]);
                float cold = c_lds[bi][c];
                float cn = m * ((1.f - ig) * cold + ig * jg);
                c_lds[bi][c] = cn;
                h2[q] = m * (tanhf(cn) * og);
            }
            u32 hp = (u32)f2bf(h2[0]) | ((u32)f2bf(h2[1]) << 16);
            u16* hdst = h_bf + (size_t)((dir * 2 + ((tf + 1) & 1)) * BATCH + bg) * HSTRIDE + pl * 16 + cp;
            asm volatile("global_store_dword %[a], %[d], off sc0 sc1"
                         :: [a] "v"(hdst), [d] "v"(hp) : "memory");
            float2 rv = make_float2(h2[0], h2[1]);
            *(float2*)(raw + ((size_t)t * BATCH + bg) * (2 * HID) + dir * HID + pl * 16 + cp) = rv;
        }

        // ---- inter-block barrier (25 blocks per (batch,dir) group) ----
        if (tf < T_LEN - 1) {
            __syncthreads();  // drains all vmem (incl. sc0sc1 h stores) via vmcnt(0)
            if (tid == 0) {
                int a = __hip_atomic_fetch_add(cnt, 1, __ATOMIC_RELAXED, __HIP_MEMORY_SCOPE_AGENT);
                if (a == (tf + 1) * 25 - 1) {
                    __hip_atomic_fetch_add(gen, 1, __ATOMIC_RELAXED, __HIP_MEMORY_SCOPE_AGENT);
                } else {
                    while (__hip_atomic_load(gen, __ATOMIC_RELAXED, __HIP_MEMORY_SCOPE_AGENT) <= tf)
                        __builtin_amdgcn_s_sleep(1);
                }
            }
            __syncthreads();
        }
    }

    // ---- dump final c ----
    __syncthreads();
    if (tid < 128) {
        const int bi = tid >> 3, cp = (tid & 7) * 2;
        const int bg = bb + bi;
        float* cd = c_end + (size_t)(dir * BATCH + bg) * HID + pl * 16 + cp;
        cd[0] = c_lds[bi][cp];
        cd[1] = c_lds[bi][cp + 1];
    }
}

// ---------------- save final h/c states ----------------
__global__ void save_states(const float* __restrict__ raw, const float* __restrict__ c_ws,
                            float* __restrict__ out, int layer) {
    const int n = 2 * BATCH * HID;
    for (int i = blockIdx.x * blockDim.x + threadIdx.x; i < n; i += gridDim.x * blockDim.x) {
        int d = i / (BATCH * HID);
        int rem = i - d * (BATCH * HID);
        int b = rem / HID;
        int k = rem - b * HID;
        int t = d ? 0 : (T_LEN - 1);
        float h = raw[((size_t)t * BATCH + b) * (2 * HID) + d * HID + k];
        size_t base = (size_t)T_LEN * BATCH * (2 * HID);
        size_t idx = ((size_t)(2 * layer + d) * BATCH + b) * HID + k;
        out[base + idx] = h;
        out[base + (size_t)2 * 3 * BATCH * HID + idx] = c_ws[d * (BATCH * HID) + b * HID + k];
    }
}

// ---------------- highway: gates GEMM + fused sigmoid blend ----------------
__global__ __launch_bounds__(256) void highway_gemm(
    const u16* __restrict__ A, const u16* __restrict__ Bw, const float* __restrict__ pb,
    float* __restrict__ Rcur, const float* __restrict__ Iprev)
{
    const int m0 = blockIdx.x * 128;
    const int n0 = blockIdx.y * 128;
    const int tid = threadIdx.x, lane = tid & 63, wave = tid >> 6;
    const int wy = wave >> 1, wx = wave & 1;
    const int l15 = lane & 15, hi = lane >> 4;
    const short8 zero8 = {};

    f32x4 acc[4][4] = {};
    const int arow0 = m0 + wy * 64 + l15;
    const int brow0 = n0 + wx * 64 + l15;

    for (int kk = 0; kk < 25; ++kk) {
        const int k0 = kk * 32 + 8 * hi;
        short8 a[4], b[4];
#pragma unroll
        for (int mf = 0; mf < 4; ++mf)
            a[mf] = *(const short8*)(A + (size_t)(arow0 + mf * 16) * DIN + k0);
#pragma unroll
        for (int nf = 0; nf < 4; ++nf) {
            int br = brow0 + nf * 16;
            b[nf] = (br < DIN) ? *(const short8*)(Bw + (size_t)br * DIN + k0) : zero8;
        }
#pragma unroll
        for (int mf = 0; mf < 4; ++mf)
#pragma unroll
            for (int nf = 0; nf < 4; ++nf)
                acc[mf][nf] = __builtin_amdgcn_mfma_f32_16x16x32_bf16(a[mf], b[nf], acc[mf][nf], 0, 0, 0);
    }

#pragma unroll
    for (int mf = 0; mf < 4; ++mf)
#pragma unroll
        for (int nf = 0; nf < 4; ++nf)
#pragma unroll
            for (int j = 0; j < 4; ++j) {
                int row = m0 + wy * 64 + mf * 16 + hi * 4 + j;
                int col = n0 + wx * 64 + nf * 16 + l15;
                if (col < DIN) {
                    float g = sigmoidf_(acc[mf][nf][j] + pb[col]);
                    size_t off = (size_t)row * DIN + col;
                    Rcur[off] = g * Rcur[off] + (1.f - g) * Iprev[off];
                }
            }
}

// ---------------- host ----------------
extern "C" void kernel_launch(void* const* d_in, const int* in_sizes, int n_in,
                              void* d_out, int out_size, void* d_ws, size_t ws_size,
                              hipStream_t stream) {
    const float* x      = (const float*)d_in[0];
    const float* masks  = (const float*)d_in[1];
    const float* fW     = (const float*)d_in[2];
    const float* fb     = (const float*)d_in[3];
    const float* bW     = (const float*)d_in[4];
    const float* bb     = (const float*)d_in[5];
    const float* f_init = (const float*)d_in[6];
    const float* b_init = (const float*)d_in[7];
    const float* pW     = (const float*)d_in[8];
    const float* pb     = (const float*)d_in[9];
    float* out = (float*)d_out;

    char* ws = (char*)d_ws;
    float* R0   = (float*)(ws + 0);                       // 104,857,600
    float* R1   = (float*)(ws + 104857600);               // 104,857,600
    u16* x_bf   = (u16*)(ws + 209715200);                 //  52,428,800
    u16* W_bf   = (u16*)(ws + 262144000);                 //   5,836,800
    u16* pW_bf  = (u16*)(ws + 267980800);                 //   1,280,000
    u16* h_bf   = (u16*)(ws + 269260800);                 //     212,992 ([2][2][64][416])
    float* c_ws = (float*)(ws + 269473792);               //     204,800
    int* bar    = (int*)(ws + 269678592);                 //     192 (3 layers x 16 ints)
    const int N_TB = T_LEN * BATCH * DIN;

    hipMemsetAsync(bar, 0, 3 * 16 * sizeof(int), stream);

    for (int layer = 0; layer < 3; ++layer) {
        float* raw = (layer == 0) ? R0 : (layer == 1) ? R1 : out;
        const float* inp_f32 = (layer == 0) ? x : (layer == 1) ? R0 : R1;

        cast_f32_bf16<<<4096, 256, 0, stream>>>(inp_f32, x_bf, N_TB);
        cast_W<<<4096, 256, 0, stream>>>(fW, bW, W_bf, layer);
        init_states<<<(2 * 2 * BATCH * HSTRIDE + 255) / 256, 256, 0, stream>>>(f_init, b_init, h_bf, layer);

        lstm_persist<<<dim3(25, 4, 2), 192, 0, stream>>>(
            x_bf, W_bf, fb + layer * GATES, bb + layer * GATES, masks,
            f_init + layer * 2 * HID, b_init + layer * 2 * HID,
            h_bf, c_ws, raw, bar + layer * 16);

        save_states<<<200, 256, 0, stream>>>(raw, c_ws, out, layer);

        if (layer > 0) {
            cast_f32_bf16<<<4096, 256, 0, stream>>>(raw, x_bf, N_TB);
            cast_f32_bf16<<<2048, 256, 0, stream>>>(pW + (size_t)(layer - 1) * DIN * DIN, pW_bf, DIN * DIN);
            highway_gemm<<<dim3(256, 7), 256, 0, stream>>>(
                x_bf, pW_bf, pb + (layer - 1) * DIN, raw, inp_f32);
        }
    }
}

// Round 3
// 10432.375 us; speedup vs baseline: 2.3397x; 2.3397x over previous
//
#include <hip/hip_runtime.h>

typedef __attribute__((ext_vector_type(8))) short short8;
typedef __attribute__((ext_vector_type(4))) float f32x4;
typedef unsigned short u16;
typedef unsigned int u32;

#define T_LEN 512
#define BATCH 64
#define HID 400
#define GATES 1200   // 3*HID
#define DIN 800      // layer input width (D == 2H)
#define KTOT 1200    // DIN + HID
#define WSTRIDE 1216 // K padded to 38*32
#define HSTRIDE 416  // HID padded to 13*32
#define WLDS_STRIDE 1224 // +8 halves -> byte stride 2448 -> <=2-way LDS bank aliasing

__device__ __forceinline__ u16 f2bf(float f) {
    u32 u = __builtin_bit_cast(u32, f);
    u += 0x7fffu + ((u >> 16) & 1u);
    return (u16)(u >> 16);
}
__device__ __forceinline__ float sigmoidf_(float x) { return 1.f / (1.f + expf(-x)); }

// ---------------- cast kernels ----------------
__global__ void cast_f32_bf16(const float* __restrict__ in, u16* __restrict__ out, int n) {
    for (int i = blockIdx.x * blockDim.x + threadIdx.x; i < n; i += gridDim.x * blockDim.x)
        out[i] = f2bf(in[i]);
}

// W_bf layout: [2][GATES][WSTRIDE], cols >= 1200 zeroed
__global__ void cast_W(const float* __restrict__ fW, const float* __restrict__ bW,
                       u16* __restrict__ W_bf, int layer) {
    const int n = 2 * GATES * WSTRIDE;
    for (int i = blockIdx.x * blockDim.x + threadIdx.x; i < n; i += gridDim.x * blockDim.x) {
        int d = i / (GATES * WSTRIDE);
        int rem = i - d * (GATES * WSTRIDE);
        int r = rem / WSTRIDE;
        int k = rem - r * WSTRIDE;
        const float* src = (d ? bW : fW) + (size_t)layer * GATES * KTOT;
        W_bf[i] = (k < KTOT) ? f2bf(src[(size_t)r * KTOT + k]) : (u16)0;
    }
}

// h_bf: [2 dirs][2 bufs][BATCH][HSTRIDE]; buf0 = h_init, buf1 = 0, pads zeroed
__global__ void init_states(const float* __restrict__ f_init, const float* __restrict__ b_init,
                            u16* __restrict__ h_bf, int layer) {
    const int n = 2 * 2 * BATCH * HSTRIDE;
    for (int i = blockIdx.x * blockDim.x + threadIdx.x; i < n; i += gridDim.x * blockDim.x) {
        int d = i / (2 * BATCH * HSTRIDE);
        int rem = i - d * (2 * BATCH * HSTRIDE);
        int buf = rem / (BATCH * HSTRIDE);
        int rem2 = rem - buf * (BATCH * HSTRIDE);
        int k = rem2 % HSTRIDE;
        const float* src = (d ? b_init : f_init) + layer * 2 * HID;
        h_bf[i] = (k < HID && buf == 0) ? f2bf(src[k]) : (u16)0;
    }
}

// ---------------- persistent per-layer LSTM ----------------
// grid: (25 h-col blocks, 4 batch blocks, 2 dirs) = 200 blocks, 192 threads (3 waves: gates i,j,o)
// W slice lives in LDS for the whole layer. h exchanged via sc0/sc1 coherence-point ops.
// Per (dir,batch) group of 25 blocks: monotonic counter/generation barrier, each counter on
// its own 256B line (8 groups -> no cross-group line contention).
__global__ __launch_bounds__(192) void lstm_persist(
    const u16* __restrict__ x_bf,   // [T*B, DIN]
    const u16* __restrict__ W_bf,   // [2][GATES][WSTRIDE]
    const float* __restrict__ fb_l, // [GATES]
    const float* __restrict__ bb_l, // [GATES]
    const float* __restrict__ masks,// [T*B]
    const float* __restrict__ finit,// [2,HID] (layer slice)
    const float* __restrict__ binit,// [2,HID]
    u16* __restrict__ h_bf,         // [2][2][B][HSTRIDE]
    float* __restrict__ c_end,      // [2][B][HID]
    float* __restrict__ raw,        // [T*B, 2H]
    int* __restrict__ bar)          // [1024]: cnt at g*64, gen at 512+g*64
{
    const int dir = blockIdx.z;
    const int pl  = blockIdx.x;           // 0..24 h-col block
    const int bb  = blockIdx.y * 16;      // batch base
    const int tid = threadIdx.x;
    const int lane = tid & 63, gate = tid >> 6;
    const int l15 = lane & 15, hi = lane >> 4;
    const int gid = dir * 4 + blockIdx.y;

    int* cnt = bar + gid * 64;        // own 256B line
    int* gen = bar + 512 + gid * 64;  // own 256B line

    __shared__ u16 Wlds[48 * WLDS_STRIDE];   // 117,504 B
    __shared__ float gsm[3][16][16];
    __shared__ float c_lds[16][16];

    // ---- preload W slice (48 rows x 1216) into LDS, once per layer ----
    {
        const u16* Wsrc = W_bf + (size_t)dir * GATES * WSTRIDE;
        for (int i = tid; i < 48 * (WSTRIDE / 8); i += 192) {
            int r = i / (WSTRIDE / 8);
            int c8 = (i - r * (WSTRIDE / 8)) * 8;
            int pr = (r >> 4) * HID + pl * 16 + (r & 15);
            *(short8*)&Wlds[r * WLDS_STRIDE + c8] =
                *(const short8*)(Wsrc + (size_t)pr * WSTRIDE + c8);
        }
    }

    const float* init = dir ? binit : finit;
    for (int i = tid; i < 256; i += 192)
        c_lds[i >> 4][i & 15] = init[HID + pl * 16 + (i & 15)];

    const int prow = gate * HID + pl * 16 + l15;  // W row this lane multiplies
    const float bval = (dir ? bb_l : fb_l)[prow];
    const int wb = (gate * 16 + l15) * WLDS_STRIDE + 8 * hi;  // LDS B-fragment base (halves)

    __syncthreads();

    for (int tf = 0; tf < T_LEN; ++tf) {
        const int t = dir ? (T_LEN - 1 - tf) : tf;

        // ---- issue h loads FIRST (device-coherent bypass), no wait yet ----
        const u16* Hrow = h_bf + (size_t)((dir * 2 + (tf & 1)) * BATCH + bb + l15) * HSTRIDE + 8 * hi;
        short8 hf[13];
        asm volatile(
            "global_load_dwordx4 %[f0],  %[a], off sc0 sc1\n\t"
            "global_load_dwordx4 %[f1],  %[a], off offset:64 sc0 sc1\n\t"
            "global_load_dwordx4 %[f2],  %[a], off offset:128 sc0 sc1\n\t"
            "global_load_dwordx4 %[f3],  %[a], off offset:192 sc0 sc1\n\t"
            "global_load_dwordx4 %[f4],  %[a], off offset:256 sc0 sc1\n\t"
            "global_load_dwordx4 %[f5],  %[a], off offset:320 sc0 sc1\n\t"
            "global_load_dwordx4 %[f6],  %[a], off offset:384 sc0 sc1\n\t"
            "global_load_dwordx4 %[f7],  %[a], off offset:448 sc0 sc1\n\t"
            "global_load_dwordx4 %[f8],  %[a], off offset:512 sc0 sc1\n\t"
            "global_load_dwordx4 %[f9],  %[a], off offset:576 sc0 sc1\n\t"
            "global_load_dwordx4 %[f10], %[a], off offset:640 sc0 sc1\n\t"
            "global_load_dwordx4 %[f11], %[a], off offset:704 sc0 sc1\n\t"
            "global_load_dwordx4 %[f12], %[a], off offset:768 sc0 sc1"
            : [f0] "=&v"(hf[0]), [f1] "=&v"(hf[1]), [f2] "=&v"(hf[2]), [f3] "=&v"(hf[3]),
              [f4] "=&v"(hf[4]), [f5] "=&v"(hf[5]), [f6] "=&v"(hf[6]), [f7] "=&v"(hf[7]),
              [f8] "=&v"(hf[8]), [f9] "=&v"(hf[9]), [f10] "=&v"(hf[10]), [f11] "=&v"(hf[11]),
              [f12] "=&v"(hf[12])
            : [a] "v"(Hrow)
            : "memory");

        // ---- x part (K = 0..800): A from global (L2), B from LDS; hides h-load latency ----
        f32x4 acc = {bval, bval, bval, bval};
        const u16* Arow = x_bf + (size_t)(t * BATCH + bb + l15) * DIN + 8 * hi;
#pragma unroll
        for (int kk = 0; kk < 25; ++kk)
            acc = __builtin_amdgcn_mfma_f32_16x16x32_bf16(
                *(const short8*)(Arow + kk * 32),
                *(const short8*)&Wlds[wb + kk * 32], acc, 0, 0, 0);

        // ---- wait h loads, then h part (K = 800..1216) ----
        asm volatile("s_waitcnt vmcnt(0)" ::: "memory");
        __builtin_amdgcn_sched_barrier(0);
#pragma unroll
        for (int kk = 0; kk < 13; ++kk)
            acc = __builtin_amdgcn_mfma_f32_16x16x32_bf16(
                hf[kk], *(const short8*)&Wlds[wb + (25 + kk) * 32], acc, 0, 0, 0);

        // ---- gate exchange ----
#pragma unroll
        for (int j = 0; j < 4; ++j) gsm[gate][hi * 4 + j][l15] = acc[j];
        __syncthreads();

        // ---- cell update: 128 threads handle 16 batch x 8 col-pairs ----
        if (tid < 128) {
            const int bi = tid >> 3, cp = (tid & 7) * 2;
            const int bg = bb + bi;
            const float m = masks[t * BATCH + bg];
            float h2[2];
#pragma unroll
            for (int q = 0; q < 2; ++q) {
                const int c = cp + q;
                float ig = sigmoidf_(gsm[0][bi][c]);
                float jg = tanhf(gsm[1][bi][c]);
                float og = sigmoidf_(gsm[2][bi][c]);
                float cold = c_lds[bi][c];
                float cn = m * ((1.f - ig) * cold + ig * jg);
                c_lds[bi][c] = cn;
                h2[q] = m * (tanhf(cn) * og);
            }
            u32 hp = (u32)f2bf(h2[0]) | ((u32)f2bf(h2[1]) << 16);
            u16* hdst = h_bf + (size_t)((dir * 2 + ((tf + 1) & 1)) * BATCH + bg) * HSTRIDE + pl * 16 + cp;
            asm volatile("global_store_dword %[a], %[d], off sc0 sc1"
                         :: [a] "v"(hdst), [d] "v"(hp) : "memory");
            float2 rv = make_float2(h2[0], h2[1]);
            *(float2*)(raw + ((size_t)t * BATCH + bg) * (2 * HID) + dir * HID + pl * 16 + cp) = rv;
        }

        // ---- inter-block barrier (25 blocks per (dir,batch) group) ----
        if (tf < T_LEN - 1) {
            __syncthreads();  // drains vmem (incl. sc0sc1 h stores) via vmcnt(0)
            if (tid == 0) {
                int a = __hip_atomic_fetch_add(cnt, 1, __ATOMIC_RELAXED, __HIP_MEMORY_SCOPE_AGENT);
                if (a == (tf + 1) * 25 - 1) {
                    __hip_atomic_fetch_add(gen, 1, __ATOMIC_RELAXED, __HIP_MEMORY_SCOPE_AGENT);
                } else {
                    while (__hip_atomic_load(gen, __ATOMIC_RELAXED, __HIP_MEMORY_SCOPE_AGENT) <= tf)
                        __builtin_amdgcn_s_sleep(2);
                }
            }
            __syncthreads();
        }
    }

    // ---- dump final c ----
    __syncthreads();
    if (tid < 128) {
        const int bi = tid >> 3, cp = (tid & 7) * 2;
        const int bg = bb + bi;
        float* cd = c_end + (size_t)(dir * BATCH + bg) * HID + pl * 16 + cp;
        cd[0] = c_lds[bi][cp];
        cd[1] = c_lds[bi][cp + 1];
    }
}

// ---------------- save final h/c states ----------------
__global__ void save_states(const float* __restrict__ raw, const float* __restrict__ c_ws,
                            float* __restrict__ out, int layer) {
    const int n = 2 * BATCH * HID;
    for (int i = blockIdx.x * blockDim.x + threadIdx.x; i < n; i += gridDim.x * blockDim.x) {
        int d = i / (BATCH * HID);
        int rem = i - d * (BATCH * HID);
        int b = rem / HID;
        int k = rem - b * HID;
        int t = d ? 0 : (T_LEN - 1);
        float h = raw[((size_t)t * BATCH + b) * (2 * HID) + d * HID + k];
        size_t base = (size_t)T_LEN * BATCH * (2 * HID);
        size_t idx = ((size_t)(2 * layer + d) * BATCH + b) * HID + k;
        out[base + idx] = h;
        out[base + (size_t)2 * 3 * BATCH * HID + idx] = c_ws[d * (BATCH * HID) + b * HID + k];
    }
}

// ---------------- highway: gates GEMM + fused sigmoid blend ----------------
__global__ __launch_bounds__(256) void highway_gemm(
    const u16* __restrict__ A, const u16* __restrict__ Bw, const float* __restrict__ pb,
    float* __restrict__ Rcur, const float* __restrict__ Iprev)
{
    const int m0 = blockIdx.x * 128;
    const int n0 = blockIdx.y * 128;
    const int tid = threadIdx.x, lane = tid & 63, wave = tid >> 6;
    const int wy = wave >> 1, wx = wave & 1;
    const int l15 = lane & 15, hi = lane >> 4;
    const short8 zero8 = {};

    f32x4 acc[4][4] = {};
    const int arow0 = m0 + wy * 64 + l15;
    const int brow0 = n0 + wx * 64 + l15;

    for (int kk = 0; kk < 25; ++kk) {
        const int k0 = kk * 32 + 8 * hi;
        short8 a[4], b[4];
#pragma unroll
        for (int mf = 0; mf < 4; ++mf)
            a[mf] = *(const short8*)(A + (size_t)(arow0 + mf * 16) * DIN + k0);
#pragma unroll
        for (int nf = 0; nf < 4; ++nf) {
            int br = brow0 + nf * 16;
            b[nf] = (br < DIN) ? *(const short8*)(Bw + (size_t)br * DIN + k0) : zero8;
        }
#pragma unroll
        for (int mf = 0; mf < 4; ++mf)
#pragma unroll
            for (int nf = 0; nf < 4; ++nf)
                acc[mf][nf] = __builtin_amdgcn_mfma_f32_16x16x32_bf16(a[mf], b[nf], acc[mf][nf], 0, 0, 0);
    }

#pragma unroll
    for (int mf = 0; mf < 4; ++mf)
#pragma unroll
        for (int nf = 0; nf < 4; ++nf)
#pragma unroll
            for (int j = 0; j < 4; ++j) {
                int row = m0 + wy * 64 + mf * 16 + hi * 4 + j;
                int col = n0 + wx * 64 + nf * 16 + l15;
                if (col < DIN) {
                    float g = sigmoidf_(acc[mf][nf][j] + pb[col]);
                    size_t off = (size_t)row * DIN + col;
                    Rcur[off] = g * Rcur[off] + (1.f - g) * Iprev[off];
                }
            }
}

// ---------------- host ----------------
extern "C" void kernel_launch(void* const* d_in, const int* in_sizes, int n_in,
                              void* d_out, int out_size, void* d_ws, size_t ws_size,
                              hipStream_t stream) {
    const float* x      = (const float*)d_in[0];
    const float* masks  = (const float*)d_in[1];
    const float* fW     = (const float*)d_in[2];
    const float* fb     = (const float*)d_in[3];
    const float* bW     = (const float*)d_in[4];
    const float* bb     = (const float*)d_in[5];
    const float* f_init = (const float*)d_in[6];
    const float* b_init = (const float*)d_in[7];
    const float* pW     = (const float*)d_in[8];
    const float* pb     = (const float*)d_in[9];
    float* out = (float*)d_out;

    char* ws = (char*)d_ws;
    float* R0   = (float*)(ws + 0);                       // 104,857,600
    float* R1   = (float*)(ws + 104857600);               // 104,857,600
    u16* x_bf   = (u16*)(ws + 209715200);                 //  52,428,800
    u16* W_bf   = (u16*)(ws + 262144000);                 //   5,836,800
    u16* pW_bf  = (u16*)(ws + 267980800);                 //   1,280,000
    u16* h_bf   = (u16*)(ws + 269260800);                 //     212,992 ([2][2][64][416])
    float* c_ws = (float*)(ws + 269473792);               //     204,800
    int* bar    = (int*)(ws + 269678592);                 //  12,288 (3 layers x 1024 ints)
    const int N_TB = T_LEN * BATCH * DIN;

    hipMemsetAsync(bar, 0, 3 * 1024 * sizeof(int), stream);

    for (int layer = 0; layer < 3; ++layer) {
        float* raw = (layer == 0) ? R0 : (layer == 1) ? R1 : out;
        const float* inp_f32 = (layer == 0) ? x : (layer == 1) ? R0 : R1;

        cast_f32_bf16<<<4096, 256, 0, stream>>>(inp_f32, x_bf, N_TB);
        cast_W<<<4096, 256, 0, stream>>>(fW, bW, W_bf, layer);
        init_states<<<(2 * 2 * BATCH * HSTRIDE + 255) / 256, 256, 0, stream>>>(f_init, b_init, h_bf, layer);

        lstm_persist<<<dim3(25, 4, 2), 192, 0, stream>>>(
            x_bf, W_bf, fb + layer * GATES, bb + layer * GATES, masks,
            f_init + layer * 2 * HID, b_init + layer * 2 * HID,
            h_bf, c_ws, raw, bar + layer * 1024);

        save_states<<<200, 256, 0, stream>>>(raw, c_ws, out, layer);

        if (layer > 0) {
            cast_f32_bf16<<<4096, 256, 0, stream>>>(raw, x_bf, N_TB);
            cast_f32_bf16<<<2048, 256, 0, stream>>>(pW + (size_t)(layer - 1) * DIN * DIN, pW_bf, DIN * DIN);
            highway_gemm<<<dim3(256, 7), 256, 0, stream>>>(
                x_bf, pW_bf, pb + (layer - 1) * DIN, raw, inp_f32);
        }
    }
}

// Round 5
// 7843.349 us; speedup vs baseline: 3.1121x; 1.3301x over previous
//
#include <hip/hip_runtime.h>

typedef __attribute__((ext_vector_type(8))) short short8;
typedef __attribute__((ext_vector_type(4))) float f32x4;
typedef unsigned short u16;
typedef unsigned int u32;

#define T_LEN 512
#define BATCH 64
#define HID 400
#define GATES 1200   // 3*HID
#define DIN 800      // layer input width (D == 2H)
#define KTOT 1200    // DIN + HID
#define WSTRIDE 1216 // K padded to 38*32
#define HSTRIDE 416  // HID padded to 13*32
#define NKK 38       // K-slices of 32

__device__ __forceinline__ u16 f2bf(float f) {
    u32 u = __builtin_bit_cast(u32, f);
    u += 0x7fffu + ((u >> 16) & 1u);
    return (u16)(u >> 16);
}
__device__ __forceinline__ float sigmoidf_(float x) { return 1.f / (1.f + expf(-x)); }

// ---------------- cast kernels ----------------
__global__ void cast_f32_bf16(const float* __restrict__ in, u16* __restrict__ out, int n) {
    for (int i = blockIdx.x * blockDim.x + threadIdx.x; i < n; i += gridDim.x * blockDim.x)
        out[i] = f2bf(in[i]);
}

// W_bf layout: [2][GATES][WSTRIDE], cols >= 1200 zeroed
__global__ void cast_W(const float* __restrict__ fW, const float* __restrict__ bW,
                       u16* __restrict__ W_bf, int layer) {
    const int n = 2 * GATES * WSTRIDE;
    for (int i = blockIdx.x * blockDim.x + threadIdx.x; i < n; i += gridDim.x * blockDim.x) {
        int d = i / (GATES * WSTRIDE);
        int rem = i - d * (GATES * WSTRIDE);
        int r = rem / WSTRIDE;
        int k = rem - r * WSTRIDE;
        const float* src = (d ? bW : fW) + (size_t)layer * GATES * KTOT;
        W_bf[i] = (k < KTOT) ? f2bf(src[(size_t)r * KTOT + k]) : (u16)0;
    }
}

// h_bf: [2 dirs][2 bufs][BATCH][HSTRIDE]; buf0 = h_init, buf1 = 0, pads zeroed
__global__ void init_states(const float* __restrict__ f_init, const float* __restrict__ b_init,
                            u16* __restrict__ h_bf, int layer) {
    const int n = 2 * 2 * BATCH * HSTRIDE;
    for (int i = blockIdx.x * blockDim.x + threadIdx.x; i < n; i += gridDim.x * blockDim.x) {
        int d = i / (2 * BATCH * HSTRIDE);
        int rem = i - d * (2 * BATCH * HSTRIDE);
        int buf = rem / (BATCH * HSTRIDE);
        int rem2 = rem - buf * (BATCH * HSTRIDE);
        int k = rem2 % HSTRIDE;
        const float* src = (d ? b_init : f_init) + layer * 2 * HID;
        h_bf[i] = (k < HID && buf == 0) ? f2bf(src[k]) : (u16)0;
    }
}

// issue 25 plain 16B loads (x for a step), no wait
__device__ __forceinline__ void load_x25(const u16* p, short8* d) {
    asm volatile(
        "global_load_dwordx4 %0,  %25, off\n\t"
        "global_load_dwordx4 %1,  %25, off offset:64\n\t"
        "global_load_dwordx4 %2,  %25, off offset:128\n\t"
        "global_load_dwordx4 %3,  %25, off offset:192\n\t"
        "global_load_dwordx4 %4,  %25, off offset:256\n\t"
        "global_load_dwordx4 %5,  %25, off offset:320\n\t"
        "global_load_dwordx4 %6,  %25, off offset:384\n\t"
        "global_load_dwordx4 %7,  %25, off offset:448\n\t"
        "global_load_dwordx4 %8,  %25, off offset:512\n\t"
        "global_load_dwordx4 %9,  %25, off offset:576\n\t"
        "global_load_dwordx4 %10, %25, off offset:640\n\t"
        "global_load_dwordx4 %11, %25, off offset:704\n\t"
        "global_load_dwordx4 %12, %25, off offset:768\n\t"
        "global_load_dwordx4 %13, %25, off offset:832\n\t"
        "global_load_dwordx4 %14, %25, off offset:896\n\t"
        "global_load_dwordx4 %15, %25, off offset:960\n\t"
        "global_load_dwordx4 %16, %25, off offset:1024\n\t"
        "global_load_dwordx4 %17, %25, off offset:1088\n\t"
        "global_load_dwordx4 %18, %25, off offset:1152\n\t"
        "global_load_dwordx4 %19, %25, off offset:1216\n\t"
        "global_load_dwordx4 %20, %25, off offset:1280\n\t"
        "global_load_dwordx4 %21, %25, off offset:1344\n\t"
        "global_load_dwordx4 %22, %25, off offset:1408\n\t"
        "global_load_dwordx4 %23, %25, off offset:1472\n\t"
        "global_load_dwordx4 %24, %25, off offset:1536"
        : "=&v"(d[0]), "=&v"(d[1]), "=&v"(d[2]), "=&v"(d[3]), "=&v"(d[4]),
          "=&v"(d[5]), "=&v"(d[6]), "=&v"(d[7]), "=&v"(d[8]), "=&v"(d[9]),
          "=&v"(d[10]), "=&v"(d[11]), "=&v"(d[12]), "=&v"(d[13]), "=&v"(d[14]),
          "=&v"(d[15]), "=&v"(d[16]), "=&v"(d[17]), "=&v"(d[18]), "=&v"(d[19]),
          "=&v"(d[20]), "=&v"(d[21]), "=&v"(d[22]), "=&v"(d[23]), "=&v"(d[24])
        : "v"(p)
        : "memory");
}

// ---------------- persistent per-layer LSTM ----------------
// grid: (25 h-col blocks, 4 batch blocks, 2 dirs) = 200 blocks, 192 threads (3 waves: gates i,j,o)
// W slice in LDS fragment-major (each thread stages/reads its own fragments -> identity-safe,
// conflict-free contiguous ds_read_b128). x(t) in registers, reloaded at end of step t-1 and
// committed by the end-of-step __syncthreads drain. Arrival add is fire-and-forget after the
// drain; the wait is an all-threads poll at the top of the next step, overlapped by x-MFMAs
// running while the coherent h loads are in flight.
__global__ __launch_bounds__(192, 1) void lstm_persist(
    const u16* __restrict__ x_bf,   // [T*B, DIN]
    const u16* __restrict__ W_bf,   // [2][GATES][WSTRIDE]
    const float* __restrict__ fb_l, // [GATES]
    const float* __restrict__ bb_l, // [GATES]
    const float* __restrict__ masks,// [T*B]
    const float* __restrict__ finit,// [2,HID] (layer slice)
    const float* __restrict__ binit,// [2,HID]
    u16* __restrict__ h_bf,         // [2][2][B][HSTRIDE]
    float* __restrict__ c_end,      // [2][B][HID]
    float* __restrict__ raw,        // [T*B, 2H]
    int* __restrict__ bar)          // cnt at gid*64 (own 256B line)
{
    const int dir = blockIdx.z;
    const int pl  = blockIdx.x;           // 0..24 h-col block
    const int bb  = blockIdx.y * 16;      // batch base
    const int tid = threadIdx.x;
    const int lane = tid & 63, gate = tid >> 6;
    const int l15 = lane & 15, hi = lane >> 4;
    const int gid = dir * 4 + blockIdx.y;

    int* cnt = bar + gid * 64;        // own 256B line

    // fragment-major W: thread tid's kk-th fragment at halves (kk*192+tid)*8
    __shared__ u16 Wlds[NKK * 192 * 8];      // 116,736 B
    __shared__ float gsm[3][16][16];
    __shared__ float c_lds[16][16];

    // ---- preload W slice into LDS (identity per-thread staging), once per layer ----
    {
        const u16* Wsrc = W_bf + (size_t)dir * GATES * WSTRIDE;
        const int pr = gate * HID + pl * 16 + l15;      // this thread's W row
        const int k0 = 8 * hi;
        for (int kk = 0; kk < NKK; ++kk)
            *(short8*)&Wlds[(size_t)(kk * 192 + tid) * 8] =
                *(const short8*)(Wsrc + (size_t)pr * WSTRIDE + kk * 32 + k0);
    }

    const float* init = dir ? binit : finit;
    for (int i = tid; i < 256; i += 192)
        c_lds[i >> 4][i & 15] = init[HID + pl * 16 + (i & 15)];

    const int prow = gate * HID + pl * 16 + l15;
    const float bval = (dir ? bb_l : fb_l)[prow];
    const u16* wfrag = &Wlds[(size_t)tid * 8];      // + kk*1536 halves per slice

    const int bi_c = (tid >> 3) & 15;               // cell-update batch row (clamped for tid>=128)

    __syncthreads();

    // ---- prologue: load x for step 0, commit ----
    short8 xc[25];
    {
        const int t0 = dir ? (T_LEN - 1) : 0;
        load_x25(x_bf + (size_t)(t0 * BATCH + bb + l15) * DIN + 8 * hi, xc);
        asm volatile("s_waitcnt vmcnt(0)" ::: "memory");
        __builtin_amdgcn_sched_barrier(0);
    }

    for (int tf = 0; tf < T_LEN; ++tf) {
        const int t = dir ? (T_LEN - 1 - tf) : tf;

        // ---- wait for previous step's group arrival (all threads poll) ----
        if (tf > 0) {
            const int target = 25 * tf;
            while (__hip_atomic_load(cnt, __ATOMIC_RELAXED, __HIP_MEMORY_SCOPE_AGENT) < target)
                __builtin_amdgcn_s_sleep(1);
        }

        // ---- issue h loads (coherent bypass) + mask (plain), no wait ----
        const u16* Hrow = h_bf + (size_t)((dir * 2 + (tf & 1)) * BATCH + bb + l15) * HSTRIDE + 8 * hi;
        const float* maddr = masks + t * BATCH + bb + bi_c;
        short8 hf[13];
        float mreg;
        asm volatile(
            "global_load_dwordx4 %0,  %14, off sc0 sc1\n\t"
            "global_load_dwordx4 %1,  %14, off offset:64 sc0 sc1\n\t"
            "global_load_dwordx4 %2,  %14, off offset:128 sc0 sc1\n\t"
            "global_load_dwordx4 %3,  %14, off offset:192 sc0 sc1\n\t"
            "global_load_dwordx4 %4,  %14, off offset:256 sc0 sc1\n\t"
            "global_load_dwordx4 %5,  %14, off offset:320 sc0 sc1\n\t"
            "global_load_dwordx4 %6,  %14, off offset:384 sc0 sc1\n\t"
            "global_load_dwordx4 %7,  %14, off offset:448 sc0 sc1\n\t"
            "global_load_dwordx4 %8,  %14, off offset:512 sc0 sc1\n\t"
            "global_load_dwordx4 %9,  %14, off offset:576 sc0 sc1\n\t"
            "global_load_dwordx4 %10, %14, off offset:640 sc0 sc1\n\t"
            "global_load_dwordx4 %11, %14, off offset:704 sc0 sc1\n\t"
            "global_load_dwordx4 %12, %14, off offset:768 sc0 sc1\n\t"
            "global_load_dword   %13, %15, off"
            : "=&v"(hf[0]), "=&v"(hf[1]), "=&v"(hf[2]), "=&v"(hf[3]), "=&v"(hf[4]),
              "=&v"(hf[5]), "=&v"(hf[6]), "=&v"(hf[7]), "=&v"(hf[8]), "=&v"(hf[9]),
              "=&v"(hf[10]), "=&v"(hf[11]), "=&v"(hf[12]), "=&v"(mreg)
            : "v"(Hrow), "v"(maddr)
            : "memory");

        // ---- x part (K = 0..800): xc regs x LDS W, overlaps h-load latency ----
        f32x4 acc = {bval, bval, bval, bval};
#pragma unroll
        for (int kk = 0; kk < 25; ++kk)
            acc = __builtin_amdgcn_mfma_f32_16x16x32_bf16(
                xc[kk], *(const short8*)(wfrag + (size_t)kk * 1536), acc, 0, 0, 0);

        // ---- wait h, then h part (K = 800..1216) ----
        asm volatile("s_waitcnt vmcnt(0)" ::: "memory");
        __builtin_amdgcn_sched_barrier(0);
#pragma unroll
        for (int kk = 0; kk < 13; ++kk)
            acc = __builtin_amdgcn_mfma_f32_16x16x32_bf16(
                hf[kk], *(const short8*)(wfrag + (size_t)(25 + kk) * 1536), acc, 0, 0, 0);

        // ---- gate exchange ----
#pragma unroll
        for (int j = 0; j < 4; ++j) gsm[gate][hi * 4 + j][l15] = acc[j];
        __syncthreads();

        // ---- cell update: 128 threads, 16 batch x 8 col-pairs ----
        if (tid < 128) {
            const int bi = tid >> 3, cp = (tid & 7) * 2;
            const int bg = bb + bi;
            const float m = mreg;
            float h2[2];
#pragma unroll
            for (int q = 0; q < 2; ++q) {
                const int c = cp + q;
                float ig = sigmoidf_(gsm[0][bi][c]);
                float jg = tanhf(gsm[1][bi][c]);
                float og = sigmoidf_(gsm[2][bi][c]);
                float cold = c_lds[bi][c];
                float cn = m * ((1.f - ig) * cold + ig * jg);
                c_lds[bi][c] = cn;
                h2[q] = m * (tanhf(cn) * og);
            }
            u32 hp = (u32)f2bf(h2[0]) | ((u32)f2bf(h2[1]) << 16);
            u16* hdst = h_bf + (size_t)((dir * 2 + ((tf + 1) & 1)) * BATCH + bg) * HSTRIDE + pl * 16 + cp;
            asm volatile("global_store_dword %[a], %[d], off sc0 sc1"
                         :: [a] "v"(hdst), [d] "v"(hp) : "memory");
            float2 rv = make_float2(h2[0], h2[1]);
            *(float2*)(raw + ((size_t)t * BATCH + bg) * (2 * HID) + dir * HID + pl * 16 + cp) = rv;
        }

        // ---- reload xc for next step (committed by the syncthreads drain below) ----
        if (tf < T_LEN - 1) {
            const int tn = dir ? (T_LEN - 2 - tf) : tf + 1;
            load_x25(x_bf + (size_t)(tn * BATCH + bb + l15) * DIN + 8 * hi, xc);
        }

        // ---- drain everything (per-wave vmcnt(0) at barrier), then fire arrival ----
        __syncthreads();
        __builtin_amdgcn_sched_barrier(0);
        if (tf < T_LEN - 1 && tid == 0)
            (void)__hip_atomic_fetch_add(cnt, 1, __ATOMIC_RELAXED, __HIP_MEMORY_SCOPE_AGENT);
    }

    // ---- dump final c ----
    if (tid < 128) {
        const int bi = tid >> 3, cp = (tid & 7) * 2;
        const int bg = bb + bi;
        float* cd = c_end + (size_t)(dir * BATCH + bg) * HID + pl * 16 + cp;
        cd[0] = c_lds[bi][cp];
        cd[1] = c_lds[bi][cp + 1];
    }
}

// ---------------- save final h/c states ----------------
__global__ void save_states(const float* __restrict__ raw, const float* __restrict__ c_ws,
                            float* __restrict__ out, int layer) {
    const int n = 2 * BATCH * HID;
    for (int i = blockIdx.x * blockDim.x + threadIdx.x; i < n; i += gridDim.x * blockDim.x) {
        int d = i / (BATCH * HID);
        int rem = i - d * (BATCH * HID);
        int b = rem / HID;
        int k = rem - b * HID;
        int t = d ? 0 : (T_LEN - 1);
        float h = raw[((size_t)t * BATCH + b) * (2 * HID) + d * HID + k];
        size_t base = (size_t)T_LEN * BATCH * (2 * HID);
        size_t idx = ((size_t)(2 * layer + d) * BATCH + b) * HID + k;
        out[base + idx] = h;
        out[base + (size_t)2 * 3 * BATCH * HID + idx] = c_ws[d * (BATCH * HID) + b * HID + k];
    }
}

// ---------------- highway: gates GEMM + fused sigmoid blend ----------------
__global__ __launch_bounds__(256) void highway_gemm(
    const u16* __restrict__ A, const u16* __restrict__ Bw, const float* __restrict__ pb,
    float* __restrict__ Rcur, const float* __restrict__ Iprev)
{
    const int m0 = blockIdx.x * 128;
    const int n0 = blockIdx.y * 128;
    const int tid = threadIdx.x, lane = tid & 63, wave = tid >> 6;
    const int wy = wave >> 1, wx = wave & 1;
    const int l15 = lane & 15, hi = lane >> 4;
    const short8 zero8 = {};

    f32x4 acc[4][4] = {};
    const int arow0 = m0 + wy * 64 + l15;
    const int brow0 = n0 + wx * 64 + l15;

    for (int kk = 0; kk < 25; ++kk) {
        const int k0 = kk * 32 + 8 * hi;
        short8 a[4], b[4];
#pragma unroll
        for (int mf = 0; mf < 4; ++mf)
            a[mf] = *(const short8*)(A + (size_t)(arow0 + mf * 16) * DIN + k0);
#pragma unroll
        for (int nf = 0; nf < 4; ++nf) {
            int br = brow0 + nf * 16;
            b[nf] = (br < DIN) ? *(const short8*)(Bw + (size_t)br * DIN + k0) : zero8;
        }
#pragma unroll
        for (int mf = 0; mf < 4; ++mf)
#pragma unroll
            for (int nf = 0; nf < 4; ++nf)
                acc[mf][nf] = __builtin_amdgcn_mfma_f32_16x16x32_bf16(a[mf], b[nf], acc[mf][nf], 0, 0, 0);
    }

#pragma unroll
    for (int mf = 0; mf < 4; ++mf)
#pragma unroll
        for (int nf = 0; nf < 4; ++nf)
#pragma unroll
            for (int j = 0; j < 4; ++j) {
                int row = m0 + wy * 64 + mf * 16 + hi * 4 + j;
                int col = n0 + wx * 64 + nf * 16 + l15;
                if (col < DIN) {
                    float g = sigmoidf_(acc[mf][nf][j] + pb[col]);
                    size_t off = (size_t)row * DIN + col;
                    Rcur[off] = g * Rcur[off] + (1.f - g) * Iprev[off];
                }
            }
}

// ---------------- host ----------------
extern "C" void kernel_launch(void* const* d_in, const int* in_sizes, int n_in,
                              void* d_out, int out_size, void* d_ws, size_t ws_size,
                              hipStream_t stream) {
    const float* x      = (const float*)d_in[0];
    const float* masks  = (const float*)d_in[1];
    const float* fW     = (const float*)d_in[2];
    const float* fb     = (const float*)d_in[3];
    const float* bW     = (const float*)d_in[4];
    const float* bb     = (const float*)d_in[5];
    const float* f_init = (const float*)d_in[6];
    const float* b_init = (const float*)d_in[7];
    const float* pW     = (const float*)d_in[8];
    const float* pb     = (const float*)d_in[9];
    float* out = (float*)d_out;

    char* ws = (char*)d_ws;
    float* R0   = (float*)(ws + 0);                       // 104,857,600
    float* R1   = (float*)(ws + 104857600);               // 104,857,600
    u16* x_bf   = (u16*)(ws + 209715200);                 //  52,428,800
    u16* W_bf   = (u16*)(ws + 262144000);                 //   5,836,800
    u16* pW_bf  = (u16*)(ws + 267980800);                 //   1,280,000
    u16* h_bf   = (u16*)(ws + 269260800);                 //     212,992 ([2][2][64][416])
    float* c_ws = (float*)(ws + 269473792);               //     204,800
    int* bar    = (int*)(ws + 269678592);                 //  12,288 (3 layers x 1024 ints)
    const int N_TB = T_LEN * BATCH * DIN;

    hipMemsetAsync(bar, 0, 3 * 1024 * sizeof(int), stream);

    for (int layer = 0; layer < 3; ++layer) {
        float* raw = (layer == 0) ? R0 : (layer == 1) ? R1 : out;
        const float* inp_f32 = (layer == 0) ? x : (layer == 1) ? R0 : R1;

        cast_f32_bf16<<<4096, 256, 0, stream>>>(inp_f32, x_bf, N_TB);
        cast_W<<<4096, 256, 0, stream>>>(fW, bW, W_bf, layer);
        init_states<<<(2 * 2 * BATCH * HSTRIDE + 255) / 256, 256, 0, stream>>>(f_init, b_init, h_bf, layer);

        lstm_persist<<<dim3(25, 4, 2), 192, 0, stream>>>(
            x_bf, W_bf, fb + layer * GATES, bb + layer * GATES, masks,
            f_init + layer * 2 * HID, b_init + layer * 2 * HID,
            h_bf, c_ws, raw, bar + layer * 1024);

        save_states<<<200, 256, 0, stream>>>(raw, c_ws, out, layer);

        if (layer > 0) {
            cast_f32_bf16<<<4096, 256, 0, stream>>>(raw, x_bf, N_TB);
            cast_f32_bf16<<<2048, 256, 0, stream>>>(pW + (size_t)(layer - 1) * DIN * DIN, pW_bf, DIN * DIN);
            highway_gemm<<<dim3(256, 7), 256, 0, stream>>>(
                x_bf, pW_bf, pb + (layer - 1) * DIN, raw, inp_f32);
        }
    }
}

// Round 6
// 5660.573 us; speedup vs baseline: 4.3121x; 1.3856x over previous
//
#include <hip/hip_runtime.h>

typedef __attribute__((ext_vector_type(8))) short short8;
typedef __attribute__((ext_vector_type(4))) float f32x4;
typedef unsigned short u16;
typedef unsigned int u32;

#define T_LEN 512
#define BATCH 64
#define HID 400
#define GATES 1200   // 3*HID
#define DIN 800      // layer input width (D == 2H)
#define KTOT 1200    // DIN + HID
#define WSTRIDE 1216 // K padded to 38*32
#define HSTRIDE 416  // HID padded to 13*32
#define NKK 38       // K-slices of 32
#define FLAG_STRIDE 32   // ints (128B line) per flag

__device__ __forceinline__ u16 f2bf(float f) {
    u32 u = __builtin_bit_cast(u32, f);
    u += 0x7fffu + ((u >> 16) & 1u);
    return (u16)(u >> 16);
}
__device__ __forceinline__ float sigmoidf_(float x) { return 1.f / (1.f + expf(-x)); }

// ---------------- cast kernels ----------------
__global__ void cast_f32_bf16(const float* __restrict__ in, u16* __restrict__ out, int n) {
    for (int i = blockIdx.x * blockDim.x + threadIdx.x; i < n; i += gridDim.x * blockDim.x)
        out[i] = f2bf(in[i]);
}

// W_bf layout: [2][GATES][WSTRIDE], cols >= 1200 zeroed
__global__ void cast_W(const float* __restrict__ fW, const float* __restrict__ bW,
                       u16* __restrict__ W_bf, int layer) {
    const int n = 2 * GATES * WSTRIDE;
    for (int i = blockIdx.x * blockDim.x + threadIdx.x; i < n; i += gridDim.x * blockDim.x) {
        int d = i / (GATES * WSTRIDE);
        int rem = i - d * (GATES * WSTRIDE);
        int r = rem / WSTRIDE;
        int k = rem - r * WSTRIDE;
        const float* src = (d ? bW : fW) + (size_t)layer * GATES * KTOT;
        W_bf[i] = (k < KTOT) ? f2bf(src[(size_t)r * KTOT + k]) : (u16)0;
    }
}

// h_bf: [2 dirs][2 bufs][BATCH][HSTRIDE]; buf0 = h_init, buf1 = 0, pads zeroed
__global__ void init_states(const float* __restrict__ f_init, const float* __restrict__ b_init,
                            u16* __restrict__ h_bf, int layer) {
    const int n = 2 * 2 * BATCH * HSTRIDE;
    for (int i = blockIdx.x * blockDim.x + threadIdx.x; i < n; i += gridDim.x * blockDim.x) {
        int d = i / (2 * BATCH * HSTRIDE);
        int rem = i - d * (2 * BATCH * HSTRIDE);
        int buf = rem / (BATCH * HSTRIDE);
        int rem2 = rem - buf * (BATCH * HSTRIDE);
        int k = rem2 % HSTRIDE;
        const float* src = (d ? b_init : f_init) + layer * 2 * HID;
        h_bf[i] = (k < HID && buf == 0) ? f2bf(src[k]) : (u16)0;
    }
}

// issue 25 plain 16B loads (x for a step), no wait
__device__ __forceinline__ void load_x25(const u16* p, short8* d) {
    asm volatile(
        "global_load_dwordx4 %0,  %25, off\n\t"
        "global_load_dwordx4 %1,  %25, off offset:64\n\t"
        "global_load_dwordx4 %2,  %25, off offset:128\n\t"
        "global_load_dwordx4 %3,  %25, off offset:192\n\t"
        "global_load_dwordx4 %4,  %25, off offset:256\n\t"
        "global_load_dwordx4 %5,  %25, off offset:320\n\t"
        "global_load_dwordx4 %6,  %25, off offset:384\n\t"
        "global_load_dwordx4 %7,  %25, off offset:448\n\t"
        "global_load_dwordx4 %8,  %25, off offset:512\n\t"
        "global_load_dwordx4 %9,  %25, off offset:576\n\t"
        "global_load_dwordx4 %10, %25, off offset:640\n\t"
        "global_load_dwordx4 %11, %25, off offset:704\n\t"
        "global_load_dwordx4 %12, %25, off offset:768\n\t"
        "global_load_dwordx4 %13, %25, off offset:832\n\t"
        "global_load_dwordx4 %14, %25, off offset:896\n\t"
        "global_load_dwordx4 %15, %25, off offset:960\n\t"
        "global_load_dwordx4 %16, %25, off offset:1024\n\t"
        "global_load_dwordx4 %17, %25, off offset:1088\n\t"
        "global_load_dwordx4 %18, %25, off offset:1152\n\t"
        "global_load_dwordx4 %19, %25, off offset:1216\n\t"
        "global_load_dwordx4 %20, %25, off offset:1280\n\t"
        "global_load_dwordx4 %21, %25, off offset:1344\n\t"
        "global_load_dwordx4 %22, %25, off offset:1408\n\t"
        "global_load_dwordx4 %23, %25, off offset:1472\n\t"
        "global_load_dwordx4 %24, %25, off offset:1536"
        : "=&v"(d[0]), "=&v"(d[1]), "=&v"(d[2]), "=&v"(d[3]), "=&v"(d[4]),
          "=&v"(d[5]), "=&v"(d[6]), "=&v"(d[7]), "=&v"(d[8]), "=&v"(d[9]),
          "=&v"(d[10]), "=&v"(d[11]), "=&v"(d[12]), "=&v"(d[13]), "=&v"(d[14]),
          "=&v"(d[15]), "=&v"(d[16]), "=&v"(d[17]), "=&v"(d[18]), "=&v"(d[19]),
          "=&v"(d[20]), "=&v"(d[21]), "=&v"(d[22]), "=&v"(d[23]), "=&v"(d[24])
        : "v"(p)
        : "memory");
}

// ---------------- persistent per-layer LSTM ----------------
// grid: (25 h-col blocks, 4 batch blocks, 2 dirs) = 200 blocks, 192 threads (3 waves: gates i,j,o)
// W in LDS fragment-major (conflict-free, identity-staged). Barrier = 25 per-writer flag
// STORES (own 128B line each) + lane-parallel 25-flag poll (no RMW serialization).
// Order per step: cell+stores -> syncthreads(drain) -> flag store -> issue x(t+1) ->
// next step: poll (vmcnt(0) drains x) -> issue h loads -> x-MFMA (hides h RT) -> h-MFMA.
__global__ __launch_bounds__(192, 1) void lstm_persist(
    const u16* __restrict__ x_bf,   // [T*B, DIN]
    const u16* __restrict__ W_bf,   // [2][GATES][WSTRIDE]
    const float* __restrict__ fb_l, // [GATES]
    const float* __restrict__ bb_l, // [GATES]
    const float* __restrict__ masks,// [T*B]
    const float* __restrict__ finit,// [2,HID] (layer slice)
    const float* __restrict__ binit,// [2,HID]
    u16* __restrict__ h_bf,         // [2][2][B][HSTRIDE]
    float* __restrict__ c_end,      // [2][B][HID]
    float* __restrict__ raw,        // [T*B, 2H]
    int* __restrict__ flagsL)       // [8 groups][25 writers][FLAG_STRIDE]
{
    const int dir = blockIdx.z;
    const int pl  = blockIdx.x;           // 0..24 h-col block
    const int bb  = blockIdx.y * 16;      // batch base
    const int tid = threadIdx.x;
    const int lane = tid & 63, gate = tid >> 6;
    const int l15 = lane & 15, hi = lane >> 4;
    const int gid = dir * 4 + blockIdx.y;

    int* myflag = flagsL + (gid * 25 + pl) * FLAG_STRIDE;
    const int fl = (lane < 25) ? lane : 24;
    const int* pollp = flagsL + (gid * 25 + fl) * FLAG_STRIDE;

    // fragment-major W: thread tid's kk-th fragment at halves (kk*192+tid)*8
    __shared__ u16 Wlds[NKK * 192 * 8];      // 116,736 B
    __shared__ float gsm[3][16][16];
    __shared__ float c_lds[16][16];

    // ---- preload W slice into LDS (identity per-thread staging), once per layer ----
    {
        const u16* Wsrc = W_bf + (size_t)dir * GATES * WSTRIDE;
        const int pr = gate * HID + pl * 16 + l15;      // this thread's W row
        const int k0 = 8 * hi;
        for (int kk = 0; kk < NKK; ++kk)
            *(short8*)&Wlds[(size_t)(kk * 192 + tid) * 8] =
                *(const short8*)(Wsrc + (size_t)pr * WSTRIDE + kk * 32 + k0);
    }

    const float* init = dir ? binit : finit;
    for (int i = tid; i < 256; i += 192)
        c_lds[i >> 4][i & 15] = init[HID + pl * 16 + (i & 15)];

    const int prow = gate * HID + pl * 16 + l15;
    const float bval = (dir ? bb_l : fb_l)[prow];
    const u16* wfrag = &Wlds[(size_t)tid * 8];      // + kk*1536 halves per slice

    const int bi_c = (tid >> 3) & 15;               // cell-update batch row (clamped for tid>=128)

    __syncthreads();

    // ---- prologue: load x for step 0, commit ----
    short8 xc[25];
    {
        const int t0 = dir ? (T_LEN - 1) : 0;
        load_x25(x_bf + (size_t)(t0 * BATCH + bb + l15) * DIN + 8 * hi, xc);
        asm volatile("s_waitcnt vmcnt(0)" ::: "memory");
        __builtin_amdgcn_sched_barrier(0);
    }

    for (int tf = 0; tf < T_LEN; ++tf) {
        const int t = dir ? (T_LEN - 1 - tf) : tf;

        // ---- wait: all 25 writers' flags >= tf (lane-parallel poll, no RMW) ----
        if (tf > 0) {
            while (__hip_atomic_load(pollp, __ATOMIC_RELAXED, __HIP_MEMORY_SCOPE_AGENT) < tf)
                __builtin_amdgcn_s_sleep(1);
            asm volatile("s_waitcnt vmcnt(0)" ::: "memory");   // xc architecturally complete
            __builtin_amdgcn_sched_barrier(0);
        }

        // ---- issue h loads (coherent bypass) + mask (plain), no wait ----
        const u16* Hrow = h_bf + (size_t)((dir * 2 + (tf & 1)) * BATCH + bb + l15) * HSTRIDE + 8 * hi;
        const float* maddr = masks + t * BATCH + bb + bi_c;
        short8 hf[13];
        float mreg;
        asm volatile(
            "global_load_dwordx4 %0,  %14, off sc0 sc1\n\t"
            "global_load_dwordx4 %1,  %14, off offset:64 sc0 sc1\n\t"
            "global_load_dwordx4 %2,  %14, off offset:128 sc0 sc1\n\t"
            "global_load_dwordx4 %3,  %14, off offset:192 sc0 sc1\n\t"
            "global_load_dwordx4 %4,  %14, off offset:256 sc0 sc1\n\t"
            "global_load_dwordx4 %5,  %14, off offset:320 sc0 sc1\n\t"
            "global_load_dwordx4 %6,  %14, off offset:384 sc0 sc1\n\t"
            "global_load_dwordx4 %7,  %14, off offset:448 sc0 sc1\n\t"
            "global_load_dwordx4 %8,  %14, off offset:512 sc0 sc1\n\t"
            "global_load_dwordx4 %9,  %14, off offset:576 sc0 sc1\n\t"
            "global_load_dwordx4 %10, %14, off offset:640 sc0 sc1\n\t"
            "global_load_dwordx4 %11, %14, off offset:704 sc0 sc1\n\t"
            "global_load_dwordx4 %12, %14, off offset:768 sc0 sc1\n\t"
            "global_load_dword   %13, %15, off"
            : "=&v"(hf[0]), "=&v"(hf[1]), "=&v"(hf[2]), "=&v"(hf[3]), "=&v"(hf[4]),
              "=&v"(hf[5]), "=&v"(hf[6]), "=&v"(hf[7]), "=&v"(hf[8]), "=&v"(hf[9]),
              "=&v"(hf[10]), "=&v"(hf[11]), "=&v"(hf[12]), "=&v"(mreg)
            : "v"(Hrow), "v"(maddr)
            : "memory");

        // ---- x part (K = 0..800): xc regs x LDS W, overlaps h-load latency ----
        f32x4 acc = {bval, bval, bval, bval};
#pragma unroll
        for (int kk = 0; kk < 25; ++kk)
            acc = __builtin_amdgcn_mfma_f32_16x16x32_bf16(
                xc[kk], *(const short8*)(wfrag + (size_t)kk * 1536), acc, 0, 0, 0);

        // ---- wait h, then h part (K = 800..1216) ----
        asm volatile("s_waitcnt vmcnt(0)" ::: "memory");
        __builtin_amdgcn_sched_barrier(0);
#pragma unroll
        for (int kk = 0; kk < 13; ++kk)
            acc = __builtin_amdgcn_mfma_f32_16x16x32_bf16(
                hf[kk], *(const short8*)(wfrag + (size_t)(25 + kk) * 1536), acc, 0, 0, 0);

        // ---- gate exchange ----
#pragma unroll
        for (int j = 0; j < 4; ++j) gsm[gate][hi * 4 + j][l15] = acc[j];
        __syncthreads();

        // ---- cell update: 128 threads, 16 batch x 8 col-pairs ----
        if (tid < 128) {
            const int bi = tid >> 3, cp = (tid & 7) * 2;
            const int bg = bb + bi;
            const float m = mreg;
            float h2[2];
#pragma unroll
            for (int q = 0; q < 2; ++q) {
                const int c = cp + q;
                float ig = sigmoidf_(gsm[0][bi][c]);
                float jg = tanhf(gsm[1][bi][c]);
                float og = sigmoidf_(gsm[2][bi][c]);
                float cold = c_lds[bi][c];
                float cn = m * ((1.f - ig) * cold + ig * jg);
                c_lds[bi][c] = cn;
                h2[q] = m * (tanhf(cn) * og);
            }
            u32 hp = (u32)f2bf(h2[0]) | ((u32)f2bf(h2[1]) << 16);
            u16* hdst = h_bf + (size_t)((dir * 2 + ((tf + 1) & 1)) * BATCH + bg) * HSTRIDE + pl * 16 + cp;
            asm volatile("global_store_dword %[a], %[d], off sc0 sc1"
                         :: [a] "v"(hdst), [d] "v"(hp) : "memory");
            float2 rv = make_float2(h2[0], h2[1]);
            *(float2*)(raw + ((size_t)t * BATCH + bg) * (2 * HID) + dir * HID + pl * 16 + cp) = rv;
        }

        // ---- drain stores (per-wave vmcnt(0) at barrier), signal, then prefetch x ----
        __syncthreads();
        if (tf < T_LEN - 1) {
            if (tid == 0)
                __hip_atomic_store(myflag, tf + 1, __ATOMIC_RELAXED, __HIP_MEMORY_SCOPE_AGENT);
            const int tn = dir ? (T_LEN - 2 - tf) : tf + 1;
            load_x25(x_bf + (size_t)(tn * BATCH + bb + l15) * DIN + 8 * hi, xc);
        }
    }

    // ---- dump final c ----
    if (tid < 128) {
        const int bi = tid >> 3, cp = (tid & 7) * 2;
        const int bg = bb + bi;
        float* cd = c_end + (size_t)(dir * BATCH + bg) * HID + pl * 16 + cp;
        cd[0] = c_lds[bi][cp];
        cd[1] = c_lds[bi][cp + 1];
    }
}

// ---------------- save final h/c states ----------------
__global__ void save_states(const float* __restrict__ raw, const float* __restrict__ c_ws,
                            float* __restrict__ out, int layer) {
    const int n = 2 * BATCH * HID;
    for (int i = blockIdx.x * blockDim.x + threadIdx.x; i < n; i += gridDim.x * blockDim.x) {
        int d = i / (BATCH * HID);
        int rem = i - d * (BATCH * HID);
        int b = rem / HID;
        int k = rem - b * HID;
        int t = d ? 0 : (T_LEN - 1);
        float h = raw[((size_t)t * BATCH + b) * (2 * HID) + d * HID + k];
        size_t base = (size_t)T_LEN * BATCH * (2 * HID);
        size_t idx = ((size_t)(2 * layer + d) * BATCH + b) * HID + k;
        out[base + idx] = h;
        out[base + (size_t)2 * 3 * BATCH * HID + idx] = c_ws[d * (BATCH * HID) + b * HID + k];
    }
}

// ---------------- highway: gates GEMM + fused sigmoid blend ----------------
__global__ __launch_bounds__(256) void highway_gemm(
    const u16* __restrict__ A, const u16* __restrict__ Bw, const float* __restrict__ pb,
    float* __restrict__ Rcur, const float* __restrict__ Iprev)
{
    const int m0 = blockIdx.x * 128;
    const int n0 = blockIdx.y * 128;
    const int tid = threadIdx.x, lane = tid & 63, wave = tid >> 6;
    const int wy = wave >> 1, wx = wave & 1;
    const int l15 = lane & 15, hi = lane >> 4;
    const short8 zero8 = {};

    f32x4 acc[4][4] = {};
    const int arow0 = m0 + wy * 64 + l15;
    const int brow0 = n0 + wx * 64 + l15;

    for (int kk = 0; kk < 25; ++kk) {
        const int k0 = kk * 32 + 8 * hi;
        short8 a[4], b[4];
#pragma unroll
        for (int mf = 0; mf < 4; ++mf)
            a[mf] = *(const short8*)(A + (size_t)(arow0 + mf * 16) * DIN + k0);
#pragma unroll
        for (int nf = 0; nf < 4; ++nf) {
            int br = brow0 + nf * 16;
            b[nf] = (br < DIN) ? *(const short8*)(Bw + (size_t)br * DIN + k0) : zero8;
        }
#pragma unroll
        for (int mf = 0; mf < 4; ++mf)
#pragma unroll
            for (int nf = 0; nf < 4; ++nf)
                acc[mf][nf] = __builtin_amdgcn_mfma_f32_16x16x32_bf16(a[mf], b[nf], acc[mf][nf], 0, 0, 0);
    }

#pragma unroll
    for (int mf = 0; mf < 4; ++mf)
#pragma unroll
        for (int nf = 0; nf < 4; ++nf)
#pragma unroll
            for (int j = 0; j < 4; ++j) {
                int row = m0 + wy * 64 + mf * 16 + hi * 4 + j;
                int col = n0 + wx * 64 + nf * 16 + l15;
                if (col < DIN) {
                    float g = sigmoidf_(acc[mf][nf][j] + pb[col]);
                    size_t off = (size_t)row * DIN + col;
                    Rcur[off] = g * Rcur[off] + (1.f - g) * Iprev[off];
                }
            }
}

// ---------------- host ----------------
extern "C" void kernel_launch(void* const* d_in, const int* in_sizes, int n_in,
                              void* d_out, int out_size, void* d_ws, size_t ws_size,
                              hipStream_t stream) {
    const float* x      = (const float*)d_in[0];
    const float* masks  = (const float*)d_in[1];
    const float* fW     = (const float*)d_in[2];
    const float* fb     = (const float*)d_in[3];
    const float* bW     = (const float*)d_in[4];
    const float* bb     = (const float*)d_in[5];
    const float* f_init = (const float*)d_in[6];
    const float* b_init = (const float*)d_in[7];
    const float* pW     = (const float*)d_in[8];
    const float* pb     = (const float*)d_in[9];
    float* out = (float*)d_out;

    char* ws = (char*)d_ws;
    float* R0   = (float*)(ws + 0);                       // 104,857,600
    float* R1   = (float*)(ws + 104857600);               // 104,857,600
    u16* x_bf   = (u16*)(ws + 209715200);                 //  52,428,800
    u16* W_bf   = (u16*)(ws + 262144000);                 //   5,836,800
    u16* pW_bf  = (u16*)(ws + 267980800);                 //   1,280,000
    u16* h_bf   = (u16*)(ws + 269260800);                 //     212,992 ([2][2][64][416])
    float* c_ws = (float*)(ws + 269473792);               //     204,800
    int* bar    = (int*)(ws + 269678592);                 //  98,304 (3 layers x 8 grp x 25 x 128B)
    const int N_TB = T_LEN * BATCH * DIN;
    const int FLAGS_PER_LAYER = 8 * 25 * FLAG_STRIDE;     // 6400 ints

    hipMemsetAsync(bar, 0, 3 * FLAGS_PER_LAYER * sizeof(int), stream);

    for (int layer = 0; layer < 3; ++layer) {
        float* raw = (layer == 0) ? R0 : (layer == 1) ? R1 : out;
        const float* inp_f32 = (layer == 0) ? x : (layer == 1) ? R0 : R1;

        cast_f32_bf16<<<4096, 256, 0, stream>>>(inp_f32, x_bf, N_TB);
        cast_W<<<4096, 256, 0, stream>>>(fW, bW, W_bf, layer);
        init_states<<<(2 * 2 * BATCH * HSTRIDE + 255) / 256, 256, 0, stream>>>(f_init, b_init, h_bf, layer);

        lstm_persist<<<dim3(25, 4, 2), 192, 0, stream>>>(
            x_bf, W_bf, fb + layer * GATES, bb + layer * GATES, masks,
            f_init + layer * 2 * HID, b_init + layer * 2 * HID,
            h_bf, c_ws, raw, bar + layer * FLAGS_PER_LAYER);

        save_states<<<200, 256, 0, stream>>>(raw, c_ws, out, layer);

        if (layer > 0) {
            cast_f32_bf16<<<4096, 256, 0, stream>>>(raw, x_bf, N_TB);
            cast_f32_bf16<<<2048, 256, 0, stream>>>(pW + (size_t)(layer - 1) * DIN * DIN, pW_bf, DIN * DIN);
            highway_gemm<<<dim3(256, 7), 256, 0, stream>>>(
                x_bf, pW_bf, pb + (layer - 1) * DIN, raw, inp_f32);
        }
    }
}